// Round 3
// baseline (704.160 us; speedup 1.0000x reference)
//
#include <hip/hip_runtime.h>
#include <math.h>

#define EMB 300
#define HD  1024
#define VOC 50004
#define BB  64
#define LL  1024
#define NCH 16

typedef __attribute__((ext_vector_type(8))) short short8;
typedef __attribute__((ext_vector_type(4))) float f32x4;

// ---- workspace layout (float offsets) ----
#define WS_XT    0
#define WS_HT    (WS_XT + EMB*BB)
#define WS_HNT   (WS_HT + HD*BB)
#define WS_WYB   (WS_HNT + HD*BB)
#define WS_CTXT  (WS_WYB + HD*BB)
#define WS_AFR   (WS_CTXT + HD*BB)         // A-frag bf16 [32][4][64][8]
#define WS_SRAW  (WS_AFR + HD*BB/2 + 64)
#define WS_MPART (WS_SRAW + BB*LL)
#define WS_DPART (WS_MPART + BB*NCH)
#define WS_CPART (WS_DPART + BB*NCH)
#define WS_LSE   (WS_CPART + BB*NCH*HD)    // [64][4][2]

#define OFF_H ((size_t)BB*VOC)
#define OFF_S (OFF_H + (size_t)BB*HD)

__device__ __forceinline__ unsigned short f2bf(float f) {
  union { float f; unsigned u; } v; v.f = f;
  unsigned r = v.u + 0x7fffu + ((v.u >> 16) & 1u);
  return (unsigned short)(r >> 16);
}

// K0: gather embedding into x_T[k][b]; transpose hidden into h_T[k][b]
__global__ __launch_bounds__(256) void k0_prep(
    const int* __restrict__ input, const float* __restrict__ hidden,
    const float* __restrict__ emb, float* __restrict__ ws)
{
  const int t = blockIdx.x * 256 + threadIdx.x;
  if (t < EMB * BB) {
    const int b = t & 63, k = t >> 6;
    ws[WS_XT + t] = emb[(size_t)input[b] * EMB + k];
  }
  const int u = t - EMB * BB;
  if (u >= 0 && u < HD * BB) {
    const int b = u & 63, k = u >> 6;
    ws[WS_HT + u] = hidden[(size_t)b * HD + k];
  }
}

// K1: GRU cell. block = one j (grid 1024); lanes = b; 4 waves split K.
__global__ __launch_bounds__(256) void k1_gru(
    const float* __restrict__ w_ih, const float* __restrict__ w_hh,
    const float* __restrict__ b_ih, const float* __restrict__ b_hh,
    float* __restrict__ ws, float* __restrict__ out)
{
  __shared__ float red[4][6][64];
  const int tid = threadIdx.x;
  const int b = tid & 63;
  const int w = tid >> 6;
  const int j = blockIdx.x;
  const float* xT = ws + WS_XT;
  const float* hT = ws + WS_HT;

  const float* wr = w_ih + (size_t)j * EMB;
  const float* wz = w_ih + (size_t)(HD + j) * EMB;
  const float* wn = w_ih + (size_t)(2 * HD + j) * EMB;
  float ar = 0.f, az = 0.f, an = 0.f;
  #pragma unroll 5
  for (int kk = 0; kk < 75; ++kk) {
    const int k = w * 75 + kk;
    const float x = xT[k * 64 + b];
    ar = fmaf(wr[k], x, ar); az = fmaf(wz[k], x, az); an = fmaf(wn[k], x, an);
  }
  const float4* vr4 = (const float4*)(w_hh + (size_t)j * HD);
  const float4* vz4 = (const float4*)(w_hh + (size_t)(HD + j) * HD);
  const float4* vn4 = (const float4*)(w_hh + (size_t)(2 * HD + j) * HD);
  float hr = 0.f, hz = 0.f, hn = 0.f;
  #pragma unroll 4
  for (int kk = 0; kk < 64; ++kk) {
    const float4 r4 = vr4[w * 64 + kk];
    const float4 z4 = vz4[w * 64 + kk];
    const float4 n4 = vn4[w * 64 + kk];
    const int kb = (w * 256 + kk * 4) * 64 + b;
    const float h0 = hT[kb], h1 = hT[kb + 64], h2 = hT[kb + 128], h3 = hT[kb + 192];
    hr = fmaf(r4.x, h0, hr); hr = fmaf(r4.y, h1, hr); hr = fmaf(r4.z, h2, hr); hr = fmaf(r4.w, h3, hr);
    hz = fmaf(z4.x, h0, hz); hz = fmaf(z4.y, h1, hz); hz = fmaf(z4.z, h2, hz); hz = fmaf(z4.w, h3, hz);
    hn = fmaf(n4.x, h0, hn); hn = fmaf(n4.y, h1, hn); hn = fmaf(n4.z, h2, hn); hn = fmaf(n4.w, h3, hn);
  }
  red[w][0][b] = ar; red[w][1][b] = az; red[w][2][b] = an;
  red[w][3][b] = hr; red[w][4][b] = hz; red[w][5][b] = hn;
  __syncthreads();
  if (w == 0) {
    float s[6];
    #pragma unroll
    for (int q = 0; q < 6; ++q)
      s[q] = red[0][q][b] + red[1][q][b] + red[2][q][b] + red[3][q][b];
    const float r = 1.f / (1.f + __expf(-(s[0] + b_ih[j] + s[3] + b_hh[j])));
    const float z = 1.f / (1.f + __expf(-(s[1] + b_ih[HD + j] + s[4] + b_hh[HD + j])));
    const float n = tanhf(s[2] + b_ih[2 * HD + j] + r * (s[5] + b_hh[2 * HD + j]));
    const float h_old = hT[j * 64 + b];
    const float hnew = (1.f - z) * n + z * h_old;
    ws[WS_HNT + j * 64 + b] = hnew;
    out[OFF_H + (size_t)b * HD + j] = hnew;
  }
}

// K2: Wy = h_new @ w_attn.T + b_attn. block = one j; 4 waves split K.
__global__ __launch_bounds__(256) void k2_wy(
    const float* __restrict__ w_attn, const float* __restrict__ b_attn,
    float* __restrict__ ws)
{
  __shared__ float red[4][64];
  const int tid = threadIdx.x;
  const int b = tid & 63;
  const int w = tid >> 6;
  const int j = blockIdx.x;
  const float* hnT = ws + WS_HNT;
  const float4* w4 = (const float4*)(w_attn + (size_t)j * HD);
  float acc = 0.f;
  #pragma unroll 4
  for (int kk = 0; kk < 64; ++kk) {
    const float4 a4 = w4[w * 64 + kk];
    const int kb = (w * 256 + kk * 4) * 64 + b;
    acc = fmaf(a4.x, hnT[kb], acc);
    acc = fmaf(a4.y, hnT[kb + 64], acc);
    acc = fmaf(a4.z, hnT[kb + 128], acc);
    acc = fmaf(a4.w, hnT[kb + 192], acc);
  }
  red[w][b] = acc;
  __syncthreads();
  if (w == 0)
    ws[WS_WYB + (size_t)b * HD + j] = red[0][b] + red[1][b] + red[2][b] + red[3][b] + b_attn[j];
}

// K3: flash attention partials; lane-contiguous float4 loads.
__global__ __launch_bounds__(256) void k3_attn(
    const float* __restrict__ src, const int* __restrict__ mask,
    float* __restrict__ ws)
{
  __shared__ float m_s[4], d_s[4];
  __shared__ float c_s[4 * 1024];
  const int tid = threadIdx.x;
  const int lane = tid & 63;
  const int wave = tid >> 6;
  const int b = blockIdx.y;
  const int chunk = blockIdx.x;

  float4 wy[4];
  const float4* wb4 = (const float4*)(ws + WS_WYB + (size_t)b * HD);
  #pragma unroll
  for (int q = 0; q < 4; ++q) wy[q] = wb4[q * 64 + lane];

  float4 c[4];
  #pragma unroll
  for (int q = 0; q < 4; ++q) { c[q].x = 0.f; c[q].y = 0.f; c[q].z = 0.f; c[q].w = 0.f; }
  float m_run = -INFINITY, d_run = 0.f;
  const int l0 = chunk * 64 + wave * 16;

  for (int i = 0; i < 16; ++i) {
    const int l = l0 + i;
    const float4* sp4 = (const float4*)(src + ((size_t)l * BB + b) * HD);
    float4 va[4];
    #pragma unroll
    for (int q = 0; q < 4; ++q) va[q] = sp4[q * 64 + lane];
    float s = 0.f;
    #pragma unroll
    for (int q = 0; q < 4; ++q) {
      s = fmaf(va[q].x, wy[q].x, s); s = fmaf(va[q].y, wy[q].y, s);
      s = fmaf(va[q].z, wy[q].z, s); s = fmaf(va[q].w, wy[q].w, s);
    }
    #pragma unroll
    for (int off = 32; off > 0; off >>= 1) s += __shfl_xor(s, off);

    const int msk = mask[(size_t)b * LL + l];
    if (lane == 0) ws[WS_SRAW + (size_t)b * LL + l] = msk ? -INFINITY : s;
    if (!msk) {
      if (s > m_run) {
        const float sc = __expf(m_run - s);
        m_run = s; d_run *= sc;
        #pragma unroll
        for (int q = 0; q < 4; ++q) {
          c[q].x *= sc; c[q].y *= sc; c[q].z *= sc; c[q].w *= sc;
        }
      }
      const float p = __expf(s - m_run);
      d_run += p;
      #pragma unroll
      for (int q = 0; q < 4; ++q) {
        c[q].x = fmaf(p, va[q].x, c[q].x); c[q].y = fmaf(p, va[q].y, c[q].y);
        c[q].z = fmaf(p, va[q].z, c[q].z); c[q].w = fmaf(p, va[q].w, c[q].w);
      }
    }
  }

  if (lane == 0) { m_s[wave] = m_run; d_s[wave] = d_run; }
  float4* cs4 = (float4*)c_s;
  #pragma unroll
  for (int q = 0; q < 4; ++q) cs4[wave * 256 + q * 64 + lane] = c[q];
  __syncthreads();

  float M = -INFINITY;
  #pragma unroll
  for (int w = 0; w < 4; ++w) if (d_s[w] > 0.f) M = fmaxf(M, m_s[w]);
  float e[4]; float D = 0.f;
  #pragma unroll
  for (int w = 0; w < 4; ++w) {
    e[w] = (d_s[w] > 0.f) ? __expf(m_s[w] - M) : 0.f;
    D += d_s[w] * e[w];
  }
  float4 a; a.x = a.y = a.z = a.w = 0.f;
  #pragma unroll
  for (int w = 0; w < 4; ++w) {
    const float4 cv = cs4[w * 256 + tid];
    a.x = fmaf(e[w], cv.x, a.x); a.y = fmaf(e[w], cv.y, a.y);
    a.z = fmaf(e[w], cv.z, a.z); a.w = fmaf(e[w], cv.w, a.w);
  }
  ((float4*)(ws + WS_CPART))[(size_t)(b * NCH + chunk) * 256 + tid] = a;
  if (tid == 0) {
    ws[WS_MPART + b * NCH + chunk] = M;
    ws[WS_DPART + b * NCH + chunk] = D;
  }
}

// K3b: combine chunk partials (slot-permuted CPART); emit context_T + scores
__global__ __launch_bounds__(256) void k3b_comb(
    float* __restrict__ ws, float* __restrict__ out)
{
  const int b = blockIdx.x;
  const int t = threadIdx.x;
  const float* mp = ws + WS_MPART + b * NCH;
  const float* dp = ws + WS_DPART + b * NCH;
  float M = -INFINITY;
  #pragma unroll
  for (int cc = 0; cc < NCH; ++cc) if (dp[cc] > 0.f) M = fmaxf(M, mp[cc]);
  float e[NCH]; float D = 0.f;
  #pragma unroll
  for (int cc = 0; cc < NCH; ++cc) {
    e[cc] = (dp[cc] > 0.f) ? __expf(mp[cc] - M) : 0.f;
    D += dp[cc] * e[cc];
  }
  const float invD = 1.f / D;
  const float4* cp4 = (const float4*)(ws + WS_CPART);
  float4 a; a.x = a.y = a.z = a.w = 0.f;
  #pragma unroll
  for (int cc = 0; cc < NCH; ++cc) {
    const float4 cv = cp4[(size_t)(b * NCH + cc) * 256 + t];
    a.x = fmaf(e[cc], cv.x, a.x); a.y = fmaf(e[cc], cv.y, a.y);
    a.z = fmaf(e[cc], cv.z, a.z); a.w = fmaf(e[cc], cv.w, a.w);
  }
  const int e0 = (t >> 6) * 256 + (t & 63) * 4;
  ws[WS_CTXT + (size_t)(e0 + 0) * 64 + b] = a.x * invD;
  ws[WS_CTXT + (size_t)(e0 + 1) * 64 + b] = a.y * invD;
  ws[WS_CTXT + (size_t)(e0 + 2) * 64 + b] = a.z * invD;
  ws[WS_CTXT + (size_t)(e0 + 3) * 64 + b] = a.w * invD;
  #pragma unroll
  for (int q = 0; q < 4; ++q) {
    const int l = t + 256 * q;
    const float s = ws[WS_SRAW + (size_t)b * LL + l];
    out[OFF_S + (size_t)b * LL + l] = __expf(s - M) * invD;
  }
}

// K4: fused = tanh([ctx,h'] @ w_lin.T + b_lin) -> bf16 MFMA A-fragment layout
__global__ __launch_bounds__(256) void k4_fused(
    const float* __restrict__ w_lin, const float* __restrict__ b_lin,
    float* __restrict__ ws)
{
  __shared__ float red[4][64];
  const int tid = threadIdx.x;
  const int b = tid & 63;
  const int w = tid >> 6;
  const int j = blockIdx.x;
  const float4* wl4 = (const float4*)(w_lin + (size_t)j * (2 * HD));
  const float* act = (w < 2) ? (ws + WS_CTXT) : (ws + WS_HNT);
  float acc = 0.f;
  #pragma unroll 4
  for (int kk = 0; kk < 128; ++kk) {
    const float4 a4 = wl4[w * 128 + kk];
    const int kb = ((w & 1) * 512 + kk * 4) * 64 + b;
    acc = fmaf(a4.x, act[kb], acc);
    acc = fmaf(a4.y, act[kb + 64], acc);
    acc = fmaf(a4.z, act[kb + 128], acc);
    acc = fmaf(a4.w, act[kb + 192], acc);
  }
  red[w][b] = acc;
  __syncthreads();
  if (w == 0) {
    const float f = tanhf(red[0][b] + red[1][b] + red[2][b] + red[3][b] + b_lin[j]);
    unsigned short* af = (unsigned short*)(ws + WS_AFR);
    const int t = j >> 5, kk = j & 31;
    const int lp = (b & 15) + 16 * (kk >> 3);
    const int mt = b >> 4;
    af[(((t * 4 + mt) * 64 + lp) << 3) + (kk & 7)] = f2bf(f);
  }
}

// K5 v3: logits via bf16 MFMA. 64-v tile (782 blocks), NO LDS/barriers:
// B-fragments loaded direct global->reg with register double-buffer prefetch.
__global__ __launch_bounds__(256, 4) void k5_logits(
    const float* __restrict__ w_out, const float* __restrict__ b_out,
    const float* __restrict__ ws, float* __restrict__ out)
{
  const int tid = threadIdx.x;
  const int lane = tid & 63;
  const int w = tid >> 6;
  const int vbase = blockIdx.x * 64;
  const unsigned short* af = (const unsigned short*)(ws + WS_AFR);

  // B-frag mapping (validated R2): lane holds B[k = kt*32 + (lane>>4)*8 + j][n = lane&15]
  const int v = vbase + w * 16 + (lane & 15);
  const int vg = (v < VOC) ? v : (VOC - 1);
  const float* wrow = w_out + (size_t)vg * HD + ((lane >> 4) << 3);

  f32x4 acc[4];
  #pragma unroll
  for (int mt = 0; mt < 4; ++mt) acc[mt] = (f32x4){0.f, 0.f, 0.f, 0.f};

  float4 c0 = *(const float4*)(wrow + 0);
  float4 c1 = *(const float4*)(wrow + 4);
  float4 c2 = *(const float4*)(wrow + 32);
  float4 c3 = *(const float4*)(wrow + 36);

  #pragma unroll 2
  for (int t = 0; t < 16; ++t) {
    float4 n0, n1, n2, n3;
    if (t < 15) {
      const float* p = wrow + (t + 1) * 64;
      n0 = *(const float4*)(p + 0);
      n1 = *(const float4*)(p + 4);
      n2 = *(const float4*)(p + 32);
      n3 = *(const float4*)(p + 36);
    }
    short8 b0, b1;
    b0[0] = (short)f2bf(c0.x); b0[1] = (short)f2bf(c0.y);
    b0[2] = (short)f2bf(c0.z); b0[3] = (short)f2bf(c0.w);
    b0[4] = (short)f2bf(c1.x); b0[5] = (short)f2bf(c1.y);
    b0[6] = (short)f2bf(c1.z); b0[7] = (short)f2bf(c1.w);
    b1[0] = (short)f2bf(c2.x); b1[1] = (short)f2bf(c2.y);
    b1[2] = (short)f2bf(c2.z); b1[3] = (short)f2bf(c2.w);
    b1[4] = (short)f2bf(c3.x); b1[5] = (short)f2bf(c3.y);
    b1[6] = (short)f2bf(c3.z); b1[7] = (short)f2bf(c3.w);

    #pragma unroll
    for (int mt = 0; mt < 4; ++mt) {
      const short8 a0 = *(const short8*)(af + ((((t * 2 + 0) * 4 + mt) * 64 + lane) << 3));
      acc[mt] = __builtin_amdgcn_mfma_f32_16x16x32_bf16(a0, b0, acc[mt], 0, 0, 0);
    }
    #pragma unroll
    for (int mt = 0; mt < 4; ++mt) {
      const short8 a1 = *(const short8*)(af + ((((t * 2 + 1) * 4 + mt) * 64 + lane) << 3));
      acc[mt] = __builtin_amdgcn_mfma_f32_16x16x32_bf16(a1, b1, acc[mt], 0, 0, 0);
    }
    c0 = n0; c1 = n1; c2 = n2; c3 = n3;
  }

  if (v < VOC) {
    const float bias = b_out[v];
    #pragma unroll
    for (int mt = 0; mt < 4; ++mt) {
      #pragma unroll
      for (int r = 0; r < 4; ++r) {
        const int brow = mt * 16 + ((lane >> 4) << 2) + r;
        out[(size_t)brow * VOC + v] = acc[mt][r] + bias;
      }
    }
  }
}

// K6: partial logsumexp; grid (4, B), each block V/4 slice
__global__ __launch_bounds__(256) void k6_lse(
    const float* __restrict__ out, float* __restrict__ ws)
{
  const int chunk = blockIdx.x, b = blockIdx.y, t = threadIdx.x;
  const int base = chunk * 12501;
  const float* row = out + (size_t)b * VOC;
  float m = -INFINITY, d = 0.f;
  for (int v = base + t; v < base + 12501; v += 256) {
    const float x = row[v];
    if (x > m) { d = d * __expf(m - x) + 1.f; m = x; }
    else d += __expf(x - m);
  }
  #pragma unroll
  for (int off = 32; off > 0; off >>= 1) {
    const float m2 = __shfl_xor(m, off);
    const float d2 = __shfl_xor(d, off);
    const float M = fmaxf(m, m2);
    d = d * __expf(m - M) + d2 * __expf(m2 - M);
    m = M;
  }
  __shared__ float ms[4], ds[4];
  if ((t & 63) == 0) { ms[t >> 6] = m; ds[t >> 6] = d; }
  __syncthreads();
  if (t == 0) {
    const float M = fmaxf(fmaxf(ms[0], ms[1]), fmaxf(ms[2], ms[3]));
    const float D = ds[0] * __expf(ms[0] - M) + ds[1] * __expf(ms[1] - M)
                  + ds[2] * __expf(ms[2] - M) + ds[3] * __expf(ms[3] - M);
    ws[WS_LSE + (b * 4 + chunk) * 2] = M;
    ws[WS_LSE + (b * 4 + chunk) * 2 + 1] = D;
  }
}

// K7: combine partial lse + subtract (float4; VOC = 4*12501 exactly)
__global__ __launch_bounds__(256) void k7_sub(
    float* __restrict__ out, const float* __restrict__ ws)
{
  const int b = blockIdx.y;
  const int i = blockIdx.x * 256 + threadIdx.x;
  const float* p = ws + WS_LSE + b * 8;
  float M = fmaxf(fmaxf(p[0], p[2]), fmaxf(p[4], p[6]));
  float D = p[1] * __expf(p[0] - M) + p[3] * __expf(p[2] - M)
          + p[5] * __expf(p[4] - M) + p[7] * __expf(p[6] - M);
  const float lse = M + __logf(D);
  if (i < 12501) {
    float4* o = (float4*)(out + (size_t)b * VOC) + i;
    float4 x = *o;
    x.x -= lse; x.y -= lse; x.z -= lse; x.w -= lse;
    *o = x;
  }
}

extern "C" void kernel_launch(void* const* d_in, const int* in_sizes, int n_in,
                              void* d_out, int out_size, void* d_ws, size_t ws_size,
                              hipStream_t stream) {
  const int*   input  = (const int*)d_in[0];
  const float* hidden = (const float*)d_in[1];
  const float* src    = (const float*)d_in[2];
  const int*   mask   = (const int*)d_in[3];
  const float* emb    = (const float*)d_in[4];
  const float* w_ih   = (const float*)d_in[5];
  const float* w_hh   = (const float*)d_in[6];
  const float* b_ih   = (const float*)d_in[7];
  const float* b_hh   = (const float*)d_in[8];
  const float* w_attn = (const float*)d_in[9];
  const float* b_attn = (const float*)d_in[10];
  const float* w_lin  = (const float*)d_in[11];
  const float* b_lin  = (const float*)d_in[12];
  const float* w_out  = (const float*)d_in[13];
  const float* b_out  = (const float*)d_in[14];
  float* out = (float*)d_out;
  float* ws  = (float*)d_ws;

  k0_prep<<<331, 256, 0, stream>>>(input, hidden, emb, ws);
  k1_gru<<<1024, 256, 0, stream>>>(w_ih, w_hh, b_ih, b_hh, ws, out);
  k2_wy<<<1024, 256, 0, stream>>>(w_attn, b_attn, ws);
  k3_attn<<<dim3(NCH, BB), 256, 0, stream>>>(src, mask, ws);
  k3b_comb<<<BB, 256, 0, stream>>>(ws, out);
  k4_fused<<<1024, 256, 0, stream>>>(w_lin, b_lin, ws);
  k5_logits<<<(VOC + 63) / 64, 256, 0, stream>>>(w_out, b_out, ws, out);
  k6_lse<<<dim3(4, BB), 256, 0, stream>>>(out, ws);
  k7_sub<<<dim3(49, BB), 256, 0, stream>>>(out, ws);
}